// Round 1
// baseline (1073.342 us; speedup 1.0000x reference)
//
#include <hip/hip_runtime.h>

// DockBoardAttention: B=65536, NDOCK=3, DCELL=25, C=32, HW=64, HD=16
// One wave64 per batch; lane = spatial position s in [0,64).

#define NWAVES 4           // waves (= batches) per block
#define VSTRIDE 68         // padded LDS row stride (words) for v/attn tiles

__global__ __launch_bounds__(256, 4) void dock_attn_kernel(
    const float* __restrict__ dock,   // [B,3,25]
    const float* __restrict__ grid,   // [B,32,64]
    const float* __restrict__ Wq,     // [16,25]
    const float* __restrict__ bq,     // [16]
    const float* __restrict__ Wk,     // [16,32]
    const float* __restrict__ bk,     // [16]
    const float* __restrict__ Wv,     // [16,32]
    const float* __restrict__ bv,     // [16]
    const float* __restrict__ Wo,     // [16,16]
    const float* __restrict__ bo,     // [16]
    float* __restrict__ out,          // [B,48]
    int b_total)
{
    __shared__ __align__(16) float WqL[400];
    __shared__ float bqL[16];
    __shared__ float WoL[16 * 17];    // padded: bank-conflict-free per-e rows
    __shared__ float boL[16];
    __shared__ __align__(16) float qL[NWAVES][48];
    __shared__ __align__(16) float vL[NWAVES][16 * VSTRIDE];
    __shared__ __align__(16) float attnL[NWAVES][3 * VSTRIDE];
    __shared__ __align__(16) float ctxL[NWAVES][48];

    const int tid = threadIdx.x;

    // ---- block-level weight preload (shared by all 4 waves) ----
    for (int i = tid; i < 400; i += 256) WqL[i] = Wq[i];
    {
        int e = tid >> 4, d = tid & 15;          // covers all 256 = 16x16
        WoL[e * 17 + d] = Wo[e * 16 + d];
    }
    if (tid < 16) { bqL[tid] = bq[tid]; boL[tid] = bo[tid]; }
    __syncthreads();

    const int wave = tid >> 6;
    const int lane = tid & 63;
    const int b = blockIdx.x * NWAVES + wave;
    if (b >= b_total) return;   // B divisible by 4, never taken; keeps it safe

    // ---- Q: lanes 0..47, lane -> (n,d); q[n][d] = dock[n,:] . Wq[d,:] + bq[d]
    if (lane < 48) {
        const int n = lane >> 4, d = lane & 15;
        const float* dptr = dock + (size_t)b * 75 + n * 25;
        float acc = bqL[d];
        #pragma unroll
        for (int c = 0; c < 25; ++c)
            acc = fmaf(dptr[c], WqL[d * 25 + c], acc);
        qL[wave][lane] = acc;
    }

    // ---- load this lane's g column: g[c] = grid[b][c][lane]  (coalesced) ----
    const float* gptr = grid + (size_t)b * 2048 + lane;
    float g[32];
    #pragma unroll
    for (int c = 0; c < 32; ++c) g[c] = gptr[c * 64];

    // ---- k,v = Wk/Wv @ g + b   (weights are wave-uniform -> scalar loads) ----
    float kk[16], vv[16];
    #pragma unroll 2
    for (int d = 0; d < 16; ++d) {
        float ka = bk[d], va = bv[d];
        #pragma unroll
        for (int c = 0; c < 32; ++c) {
            ka = fmaf(Wk[d * 32 + c], g[c], ka);
            va = fmaf(Wv[d * 32 + c], g[c], va);
        }
        kk[d] = ka; vv[d] = va;
    }

    __syncthreads();   // qL visible (also drains nothing useful: g consumed)

    // ---- scores: sc[n] = q[n,:] . k  (q broadcast from LDS) ----
    float sc[3];
    #pragma unroll
    for (int n = 0; n < 3; ++n) {
        float a = 0.f;
        #pragma unroll
        for (int d = 0; d < 16; ++d)
            a = fmaf(qL[wave][n * 16 + d], kk[d], a);
        sc[n] = a;
    }

    // ---- softmax over the 64 lanes (scale 1/sqrt(16) = 0.25 folded in) ----
    float attn[3];
    #pragma unroll
    for (int n = 0; n < 3; ++n) {
        float m = sc[n];
        #pragma unroll
        for (int off = 1; off < 64; off <<= 1)
            m = fmaxf(m, __shfl_xor(m, off));
        float e = __expf((sc[n] - m) * 0.25f);
        float ssum = e;
        #pragma unroll
        for (int off = 1; off < 64; off <<= 1)
            ssum += __shfl_xor(ssum, off);
        attn[n] = e * __builtin_amdgcn_rcpf(ssum);
    }

    // ---- stash v and attn for the cross-lane ctx reduction ----
    #pragma unroll
    for (int d = 0; d < 16; ++d) vL[wave][d * VSTRIDE + lane] = vv[d];
    #pragma unroll
    for (int n = 0; n < 3; ++n) attnL[wave][n * VSTRIDE + lane] = attn[n];

    __syncthreads();

    // ---- ctx: lanes 0..47 -> (n,d); ctx[n][d] = sum_s attn[n][s]*v[d][s] ----
    if (lane < 48) {
        const int n = lane >> 4, d = lane & 15;
        const float4* ap = (const float4*)&attnL[wave][n * VSTRIDE];
        const float4* vp = (const float4*)&vL[wave][d * VSTRIDE];
        float acc = 0.f;
        #pragma unroll
        for (int j = 0; j < 16; ++j) {
            float4 a4 = ap[j];
            float4 v4 = vp[j];
            acc = fmaf(a4.x, v4.x, acc);
            acc = fmaf(a4.y, v4.y, acc);
            acc = fmaf(a4.z, v4.z, acc);
            acc = fmaf(a4.w, v4.w, acc);
        }
        ctxL[wave][lane] = acc;
    }
    __syncthreads();

    // ---- out projection: lanes 0..47 -> (n,e) ----
    if (lane < 48) {
        const int n = lane >> 4, e = lane & 15;
        float acc = boL[e];
        #pragma unroll
        for (int d = 0; d < 16; ++d)
            acc = fmaf(ctxL[wave][n * 16 + d], WoL[e * 17 + d], acc);
        out[(size_t)b * 48 + lane] = acc;
    }
}

extern "C" void kernel_launch(void* const* d_in, const int* in_sizes, int n_in,
                              void* d_out, int out_size, void* d_ws, size_t ws_size,
                              hipStream_t stream) {
    const float* dock = (const float*)d_in[0];
    const float* grid = (const float*)d_in[1];
    const float* Wq   = (const float*)d_in[2];
    const float* bq   = (const float*)d_in[3];
    const float* Wk   = (const float*)d_in[4];
    const float* bk   = (const float*)d_in[5];
    const float* Wv   = (const float*)d_in[6];
    const float* bv   = (const float*)d_in[7];
    const float* Wo   = (const float*)d_in[8];
    const float* bo   = (const float*)d_in[9];
    float* out = (float*)d_out;

    const int b_total = in_sizes[0] / 75;          // 65536
    const int blocks = (b_total + NWAVES - 1) / NWAVES;
    dock_attn_kernel<<<blocks, 256, 0, stream>>>(
        dock, grid, Wq, bq, Wk, bk, Wv, bv, Wo, bo, out, b_total);
}

// Round 2
// 712.962 us; speedup vs baseline: 1.5055x; 1.5055x over previous
//
#include <hip/hip_runtime.h>

// DockBoardAttention: B=65536, NDOCK=3, DCELL=25, C=32, HW=64, HD=16
// One wave64 per batch, lane = spatial position. No barriers; all LDS wave-private.
//
// Algebra: sc[n][s] = sum_c A[n][c] g[c][s],  A = k*(dock@Wq^T + bq)@Wk  (q.bk cancels in softmax)
//          out[n][e] = sum_c U[e][c] z[n][c] + c0[e],  z[n][c] = sum_s attn[n][s] g[c][s]
//          U = Wo@Wv, c0 = Wo@bv + bo  (uses sum_s attn = 1)
// k = 0.25 * log2(e) folded into A so softmax uses exp2 directly.

#define NW 4
#define GTS 66   // gT row stride in words: float2 reads land 2-way on banks (free)

// ws layout (floats): M[25*32] @0, bkt[32] @800, U[16*32] @832, c0[16] @1344
__global__ void precompute_kernel(const float* __restrict__ Wq, const float* __restrict__ bq,
                                  const float* __restrict__ Wk, const float* __restrict__ Wv,
                                  const float* __restrict__ bv, const float* __restrict__ Wo,
                                  const float* __restrict__ bo, float* __restrict__ ws)
{
    const float K = 0.25f * 1.44269504088896f;
    const int t = threadIdx.x;
    for (int i = t; i < 800; i += 256) {           // M~[j][c] = K * sum_d Wq[d][j]*Wk[d][c]
        int j = i >> 5, c = i & 31;
        float s = 0.f;
        #pragma unroll
        for (int d = 0; d < 16; ++d) s += Wq[d * 25 + j] * Wk[d * 32 + c];
        ws[i] = s * K;
    }
    if (t < 32) {                                   // bkt~[c] = K * sum_d bq[d]*Wk[d][c]
        float s = 0.f;
        #pragma unroll
        for (int d = 0; d < 16; ++d) s += bq[d] * Wk[d * 32 + t];
        ws[800 + t] = s * K;
    }
    for (int i = t; i < 512; i += 256) {            // U[e][c] = sum_d Wo[e][d]*Wv[d][c]
        int e = i >> 5, c = i & 31;
        float s = 0.f;
        #pragma unroll
        for (int d = 0; d < 16; ++d) s += Wo[e * 16 + d] * Wv[d * 32 + c];
        ws[832 + i] = s;
    }
    if (t < 16) {                                   // c0[e] = sum_d Wo[e][d]*bv[d] + bo[e]
        float s = bo[t];
        #pragma unroll
        for (int d = 0; d < 16; ++d) s += Wo[t * 16 + d] * bv[d];
        ws[1344 + t] = s;
    }
}

__device__ __forceinline__ float rl(float v, int srclane) {
    return __int_as_float(__builtin_amdgcn_readlane(__float_as_int(v), srclane));
}

__global__ __launch_bounds__(256, 4) void dock_attn_kernel(
    const float* __restrict__ dock,   // [B,3,25]
    const float* __restrict__ grid,   // [B,32,64]
    const float* __restrict__ ws,     // precomputed M,bkt,U,c0
    float* __restrict__ out,          // [B,48]
    int b_total)
{
    __shared__ __align__(16) float AL[NW][96];        // A[n][c], n-major
    __shared__ __align__(16) float attnL[NW][3 * 64];
    __shared__ __align__(16) float gT[NW][32 * GTS];
    __shared__ __align__(16) float zL[NW][96];

    const int tid = threadIdx.x;
    const int w = tid >> 6, lane = tid & 63;
    const int b = blockIdx.x * NW + w;
    if (b >= b_total) return;          // never taken (B%4==0); no barriers so safe

    const float* Mg  = ws;
    const float* bkt = ws + 800;
    const float* Ug  = ws + 832;
    const float* c0  = ws + 1344;

    // ---- global loads: dock broadcast regs + this lane's g column (coalesced) ----
    float d0 = dock[(size_t)b * 75 + lane];                    // dock idx 0..63
    float d1 = (lane < 11) ? dock[(size_t)b * 75 + 64 + lane] : 0.f;  // idx 64..74
    const float* gp = grid + (size_t)b * 2048 + lane;
    float g[32];
    #pragma unroll
    for (int c = 0; c < 32; ++c) g[c] = gp[c * 64];

    // ---- A[n][c] on lanes 0..31 (c = lane); dock values via readlane (SGPR) ----
    if (lane < 32) {
        float bi = bkt[lane];
        float a0 = bi, a1 = bi, a2 = bi;
        #pragma unroll
        for (int j = 0; j < 25; ++j) {
            float m = Mg[j * 32 + lane];          // coalesced, L1-hot
            float q0 = rl(d0, j);
            float q1 = rl(d0, 25 + j);
            float q2 = (50 + j < 64) ? rl(d0, 50 + j) : rl(d1, 50 + j - 64);
            a0 = fmaf(q0, m, a0);
            a1 = fmaf(q1, m, a1);
            a2 = fmaf(q2, m, a2);
        }
        AL[w][lane] = a0; AL[w][32 + lane] = a1; AL[w][64 + lane] = a2;
    }

    // ---- scores: sc[n] = sum_c A[n][c]*g[c]  (A via broadcast float4 reads) ----
    float sc0 = 0.f, sc1 = 0.f, sc2 = 0.f;
    {
        const float4* A4 = (const float4*)&AL[w][0];
        #pragma unroll
        for (int q = 0; q < 8; ++q) {
            float4 a = A4[q], bb = A4[8 + q], cc = A4[16 + q];
            float g0 = g[4 * q], g1 = g[4 * q + 1], g2 = g[4 * q + 2], g3 = g[4 * q + 3];
            sc0 = fmaf(a.x, g0, fmaf(a.y, g1, fmaf(a.z, g2, fmaf(a.w, g3, sc0))));
            sc1 = fmaf(bb.x, g0, fmaf(bb.y, g1, fmaf(bb.z, g2, fmaf(bb.w, g3, sc1))));
            sc2 = fmaf(cc.x, g0, fmaf(cc.y, g1, fmaf(cc.z, g2, fmaf(cc.w, g3, sc2))));
        }
    }

    // ---- stash g^T rows while g regs are still live ----
    #pragma unroll
    for (int c = 0; c < 32; ++c) gT[w][c * GTS + lane] = g[c];

    // ---- softmax over 64 lanes (scores already in exp2 domain) ----
    float at0, at1, at2;
    {
        float m0 = sc0, m1 = sc1, m2 = sc2;
        #pragma unroll
        for (int off = 1; off < 64; off <<= 1) {
            m0 = fmaxf(m0, __shfl_xor(m0, off));
            m1 = fmaxf(m1, __shfl_xor(m1, off));
            m2 = fmaxf(m2, __shfl_xor(m2, off));
        }
        at0 = exp2f(sc0 - m0); at1 = exp2f(sc1 - m1); at2 = exp2f(sc2 - m2);
        float s0 = at0, s1 = at1, s2 = at2;
        #pragma unroll
        for (int off = 1; off < 64; off <<= 1) {
            s0 += __shfl_xor(s0, off);
            s1 += __shfl_xor(s1, off);
            s2 += __shfl_xor(s2, off);
        }
        at0 *= __builtin_amdgcn_rcpf(s0);
        at1 *= __builtin_amdgcn_rcpf(s1);
        at2 *= __builtin_amdgcn_rcpf(s2);
    }
    attnL[w][lane] = at0; attnL[w][64 + lane] = at1; attnL[w][128 + lane] = at2;

    // ---- z[n][c] = sum_s attn[n][s]*g[c][s]: 96 length-64 dots across the wave ----
    {   // pass 1: n = lane>>5 in {0,1}, c = lane&31
        const int n = lane >> 5, c = lane & 31;
        const float2* ar = (const float2*)&attnL[w][n * 64];
        const float2* gr = (const float2*)&gT[w][c * GTS];
        float ax = 0.f, ay = 0.f;
        #pragma unroll
        for (int j = 0; j < 32; ++j) {
            float2 a = ar[j], gg = gr[j];
            ax = fmaf(a.x, gg.x, ax);
            ay = fmaf(a.y, gg.y, ay);
        }
        zL[w][n * 32 + c] = ax + ay;
    }
    if (lane < 32) {   // pass 2: n = 2, c = lane
        const float2* ar = (const float2*)&attnL[w][128];
        const float2* gr = (const float2*)&gT[w][lane * GTS];
        float ax = 0.f, ay = 0.f;
        #pragma unroll
        for (int j = 0; j < 32; ++j) {
            float2 a = ar[j], gg = gr[j];
            ax = fmaf(a.x, gg.x, ax);
            ay = fmaf(a.y, gg.y, ay);
        }
        zL[w][64 + lane] = ax + ay;
    }

    // ---- out[n][e] = sum_c U[e][c]*z[n][c] + c0[e]  (lanes 0..47) ----
    if (lane < 48) {
        const int n = lane >> 4, e = lane & 15;
        const float4* Ur = (const float4*)(Ug + e * 32);
        const float4* zr = (const float4*)&zL[w][n * 32];
        float acc0 = c0[e], acc1 = 0.f, acc2 = 0.f, acc3 = 0.f;
        #pragma unroll
        for (int q = 0; q < 8; ++q) {
            float4 u = Ur[q], z = zr[q];
            acc0 = fmaf(u.x, z.x, acc0);
            acc1 = fmaf(u.y, z.y, acc1);
            acc2 = fmaf(u.z, z.z, acc2);
            acc3 = fmaf(u.w, z.w, acc3);
        }
        out[(size_t)b * 48 + lane] = (acc0 + acc1) + (acc2 + acc3);
    }
}

extern "C" void kernel_launch(void* const* d_in, const int* in_sizes, int n_in,
                              void* d_out, int out_size, void* d_ws, size_t ws_size,
                              hipStream_t stream) {
    const float* dock = (const float*)d_in[0];
    const float* grid = (const float*)d_in[1];
    const float* Wq   = (const float*)d_in[2];
    const float* bq   = (const float*)d_in[3];
    const float* Wk   = (const float*)d_in[4];
    // d_in[5] = bk: q.bk is constant over spatial axis -> cancels in softmax; unused
    const float* Wv   = (const float*)d_in[6];
    const float* bv   = (const float*)d_in[7];
    const float* Wo   = (const float*)d_in[8];
    const float* bo   = (const float*)d_in[9];
    float* out = (float*)d_out;
    float* ws  = (float*)d_ws;

    precompute_kernel<<<1, 256, 0, stream>>>(Wq, bq, Wk, Wv, bv, Wo, bo, ws);

    const int b_total = in_sizes[0] / 75;   // 65536
    const int blocks = (b_total + NW - 1) / NW;
    dock_attn_kernel<<<blocks, 256, 0, stream>>>(dock, grid, ws, out, b_total);
}